// Round 1
// baseline (1362.561 us; speedup 1.0000x reference)
//
#include <hip/hip_runtime.h>
#include <hip/hip_bf16.h>
#include <math.h>

#define Bc 4
#define Lc 1024
#define Dc 768
#define Hc 12
#define Ec 24
#define Mc 4
#define Pc 552
#define EMBc 768
#define BLKc 64
#define NLc 97
#define Rc (Bc*Pc)      // 2208
#define KSPLIT 12

// K1: ent_att[b,e,h,l] = mean_m attention[b,h,pos[b,e,m],l]
__global__ __launch_bounds__(256) void k_ent_att(const float* __restrict__ att,
                                                 const int* __restrict__ mpos,
                                                 float* __restrict__ ent_att){
  int blk = blockIdx.x;             // (b*E+e)*H + h
  int h  = blk % Hc;
  int be = blk / Hc;                // b*E+e
  int b  = be / Ec;
  int p0 = mpos[be*Mc+0]+1, p1 = mpos[be*Mc+1]+1;
  int p2 = mpos[be*Mc+2]+1, p3 = mpos[be*Mc+3]+1;
  const float* ab = att + ((size_t)b*Hc + h)*Lc*Lc;
  const float* a0 = ab + (size_t)p0*Lc;
  const float* a1 = ab + (size_t)p1*Lc;
  const float* a2 = ab + (size_t)p2*Lc;
  const float* a3 = ab + (size_t)p3*Lc;
  float* o = ent_att + (size_t)blk*Lc;
  for (int l = threadIdx.x; l < Lc; l += 256)
    o[l] = 0.25f*(a0[l]+a1[l]+a2[l]+a3[l]);
}

// K2: ht_att[b,p,l] = normalize_l( mean_h ent_att[b,h_idx,h,l]*ent_att[b,t_idx,h,l] )
__global__ __launch_bounds__(256) void k_ht_att(const float* __restrict__ ent_att,
                                                const int* __restrict__ hts,
                                                float* __restrict__ ht_att){
  int r = blockIdx.x;
  int b = r / Pc;
  int hi = hts[r*2+0], ti = hts[r*2+1];
  const float* eh = ent_att + (size_t)(b*Ec+hi)*Hc*Lc;
  const float* et = ent_att + (size_t)(b*Ec+ti)*Hc*Lc;
  __shared__ float raw[Lc];
  __shared__ float wsum[4];
  float lsum = 0.f;
  for (int l = threadIdx.x; l < Lc; l += 256){
    float s = 0.f;
    #pragma unroll
    for (int h = 0; h < Hc; h++) s += eh[h*Lc+l]*et[h*Lc+l];
    s *= (1.0f/Hc);
    raw[l] = s;
    lsum += s;
  }
  for (int off = 32; off; off >>= 1) lsum += __shfl_down(lsum, off);
  if ((threadIdx.x & 63) == 0) wsum[threadIdx.x>>6] = lsum;
  __syncthreads();
  float inv = 1.0f/(wsum[0]+wsum[1]+wsum[2]+wsum[3] + 1e-5f);
  float* o = ht_att + (size_t)r*Lc;
  for (int l = threadIdx.x; l < Lc; l += 256)
    o[l] = raw[l]*inv;
}

// K3: rs[b,p,d] = sum_l ht_att[b,p,l]*seq[b,l,d]  (8 p-rows per block)
__global__ __launch_bounds__(256) void k_rs(const float* __restrict__ seq,
                                            const float* __restrict__ ht_att,
                                            float* __restrict__ rs_f){
  int b  = blockIdx.x / (Pc/8);
  int pt = blockIdx.x % (Pc/8);
  int p0 = pt*8;
  __shared__ float ht[8][Lc];     // 32 KB
  for (int idx = threadIdx.x; idx < 8*Lc; idx += 256){
    int pp = idx >> 10, l = idx & (Lc-1);
    ht[pp][l] = ht_att[((size_t)(b*Pc + p0 + pp))*Lc + l];
  }
  __syncthreads();
  float acc[8][3] = {};
  const float* sb = seq + (size_t)b*Lc*Dc;
  int d0 = threadIdx.x;
  for (int l = 0; l < Lc; l++){
    float s0 = sb[(size_t)l*Dc + d0];
    float s1 = sb[(size_t)l*Dc + d0 + 256];
    float s2 = sb[(size_t)l*Dc + d0 + 512];
    #pragma unroll
    for (int pp = 0; pp < 8; pp++){
      float w = ht[pp][l];
      acc[pp][0] = fmaf(w, s0, acc[pp][0]);
      acc[pp][1] = fmaf(w, s1, acc[pp][1]);
      acc[pp][2] = fmaf(w, s2, acc[pp][2]);
    }
  }
  for (int pp = 0; pp < 8; pp++){
    float* o = rs_f + ((size_t)(b*Pc + p0 + pp))*Dc;
    o[d0] = acc[pp][0]; o[d0+256] = acc[pp][1]; o[d0+512] = acc[pp][2];
  }
}

// K4a: gather 384 distinct mention embeddings
__global__ __launch_bounds__(256) void k_gather(const float* __restrict__ seq,
                                                const int* __restrict__ mpos,
                                                float* __restrict__ ment){
  int idx = blockIdx.x*256 + threadIdx.x;     // over B*E*M*D
  int d = idx % Dc;
  int bem = idx / Dc;
  int b = bem / (Ec*Mc);
  int pos = mpos[bem] + 1;
  ment[idx] = seq[((size_t)b*Lc + pos)*Dc + d];
}

// Generic row-tiled GEMM: C[r,:] = op( concat(A1[r],A2[r]) @ W + bias ), 8 rows/block
template<int KDIM, bool TANH>
__global__ __launch_bounds__(256) void k_rowgemm(const float* __restrict__ A1,
                                                 const float* __restrict__ A2,
                                                 const float* __restrict__ W,
                                                 const float* __restrict__ bias,
                                                 float* __restrict__ C){
  __shared__ float a[8][KDIM];
  int r0 = blockIdx.x*8;
  for (int idx = threadIdx.x; idx < 8*KDIM; idx += 256){
    int rr = idx / KDIM, k = idx % KDIM;
    a[rr][k] = (k < Dc) ? A1[(size_t)(r0+rr)*Dc + k]
                        : A2[(size_t)(r0+rr)*Dc + k - Dc];
  }
  __syncthreads();
  int d0 = threadIdx.x;
  float acc0[8] = {}, acc1[8] = {}, acc2[8] = {};
  for (int k = 0; k < KDIM; k++){
    const float* wr = W + (size_t)k*Dc;
    float w0 = wr[d0], w1 = wr[d0+256], w2 = wr[d0+512];
    #pragma unroll
    for (int rr = 0; rr < 8; rr++){
      float av = a[rr][k];
      acc0[rr] = fmaf(av, w0, acc0[rr]);
      acc1[rr] = fmaf(av, w1, acc1[rr]);
      acc2[rr] = fmaf(av, w2, acc2[rr]);
    }
  }
  for (int rr = 0; rr < 8; rr++){
    float o0 = acc0[rr], o1 = acc1[rr], o2 = acc2[rr];
    if (bias){ o0 += bias[d0]; o1 += bias[d0+256]; o2 += bias[d0+512]; }
    if (TANH){ o0 = tanhf(o0); o1 = tanhf(o1); o2 = tanhf(o2); }
    float* o = C + (size_t)(r0+rr)*Dc;
    o[d0] = o0; o[d0+256] = o1; o[d0+512] = o2;
  }
}

// K6: scores -> softmax over M=4 -> weighted mention sum, both sides
__global__ __launch_bounds__(256) void k_pool(const float* __restrict__ kment,
                                              const float* __restrict__ ment,
                                              const float* __restrict__ q_c,
                                              const int* __restrict__ hts,
                                              float* __restrict__ h_ent,
                                              float* __restrict__ t_ent){
  int r = blockIdx.x;
  int b = r / Pc;
  __shared__ float q[Dc];
  __shared__ float sred[16];
  __shared__ float sw[Mc];
  for (int d = threadIdx.x; d < Dc; d += 256) q[d] = q_c[(size_t)r*Dc + d];
  __syncthreads();
  const float invs = 0.03608439182435161f;  // 1/sqrt(768)
  for (int side = 0; side < 2; side++){
    int e = hts[r*2+side];
    const float* kb = kment + (size_t)(b*Ec+e)*Mc*Dc;
    const float* mb = ment  + (size_t)(b*Ec+e)*Mc*Dc;
    float part[Mc] = {0.f,0.f,0.f,0.f};
    for (int d = threadIdx.x; d < Dc; d += 256){
      float qv = q[d];
      #pragma unroll
      for (int m = 0; m < Mc; m++) part[m] = fmaf(kb[m*Dc+d], qv, part[m]);
    }
    #pragma unroll
    for (int m = 0; m < Mc; m++)
      for (int off = 32; off; off >>= 1) part[m] += __shfl_down(part[m], off);
    if ((threadIdx.x & 63) == 0){
      int w = threadIdx.x >> 6;
      #pragma unroll
      for (int m = 0; m < Mc; m++) sred[w*4+m] = part[m];
    }
    __syncthreads();
    if (threadIdx.x == 0){
      float sc[Mc]; float mx = -1e30f;
      for (int m = 0; m < Mc; m++){
        sc[m] = (sred[m]+sred[4+m]+sred[8+m]+sred[12+m])*invs;
        mx = fmaxf(mx, sc[m]);
      }
      float ssum = 0.f;
      for (int m = 0; m < Mc; m++){ sc[m] = expf(sc[m]-mx); ssum += sc[m]; }
      float isum = 1.0f/ssum;
      for (int m = 0; m < Mc; m++) sw[m] = sc[m]*isum;
    }
    __syncthreads();
    float w0 = sw[0], w1 = sw[1], w2 = sw[2], w3 = sw[3];
    float* o = (side ? t_ent : h_ent) + (size_t)r*Dc;
    for (int d = threadIdx.x; d < Dc; d += 256)
      o[d] = w0*mb[d] + w1*mb[Dc+d] + w2*mb[2*Dc+d] + w3*mb[3*Dc+d];
    __syncthreads();
  }
}

// K8: bilinear partials. grid = (R/32)*KSPLIT, 256 thr.
// thread -> (half = tid>>7 owning 16 rows, n = tid&127 output col)
__global__ __launch_bounds__(256) void k_bilinear(const float* __restrict__ hs,
                                                  const float* __restrict__ ts,
                                                  const float* __restrict__ bil_W,
                                                  float* __restrict__ partial){
  int rt = blockIdx.x / KSPLIT;
  int kk = blockIdx.x % KSPLIT;
  int r0 = rt*32;
  int half = threadIdx.x >> 7;
  int n = threadIdx.x & 127;
  int nc = n < NLc ? n : NLc-1;
  __shared__ float hst[32][64];
  __shared__ float tst[32][64];
  __shared__ float bl[64][32];
  for (int idx = threadIdx.x; idx < 32*64; idx += 256){
    int rr = idx >> 6, j = idx & 63;
    hst[rr][j] = hs[(size_t)(r0+rr)*EMBc + kk*64 + j];
    tst[rr][j] = ts[(size_t)(r0+rr)*EMBc + kk*64 + j];
  }
  float acc[16] = {};
  const float* Wb = bil_W + (size_t)kk*64*64*NLc;
  for (int i = 0; i < 64; i++){
    __syncthreads();                 // covers tile load on i==0, bl reuse after
    #pragma unroll
    for (int q = 0; q < 8; q++){
      int idx = threadIdx.x*8 + q;   // 2048 elems / 256 thr
      int j = idx >> 5, rr = idx & 31;
      bl[j][rr] = hst[rr][i]*tst[rr][j];
    }
    __syncthreads();
    const float* Wi = Wb + (size_t)i*64*NLc;
    for (int j = 0; j < 64; j++){
      float w = Wi[j*NLc + nc];
      const float* blr = &bl[j][half*16];
      #pragma unroll
      for (int rr = 0; rr < 16; rr++)
        acc[rr] = fmaf(blr[rr], w, acc[rr]);
    }
  }
  if (n < NLc){
    for (int rr = 0; rr < 16; rr++)
      partial[((size_t)kk*Rc + (r0 + half*16 + rr))*NLc + n] = acc[rr];
  }
}

// K9: sum partials + bias
__global__ __launch_bounds__(256) void k_reduce(const float* __restrict__ partial,
                                                const float* __restrict__ bilb,
                                                float* __restrict__ out){
  int idx = blockIdx.x*256 + threadIdx.x;
  if (idx >= Rc*NLc) return;
  int n = idx % NLc;
  float s = bilb[n];
  #pragma unroll
  for (int ks = 0; ks < KSPLIT; ks++) s += partial[(size_t)ks*Rc*NLc + idx];
  out[idx] = s;
}

extern "C" void kernel_launch(void* const* d_in, const int* in_sizes, int n_in,
                              void* d_out, int out_size, void* d_ws, size_t ws_size,
                              hipStream_t stream){
  const float* seq   = (const float*)d_in[0];
  const float* att   = (const float*)d_in[1];
  const float* W_q   = (const float*)d_in[2];
  const float* W_k   = (const float*)d_in[3];
  const float* headW = (const float*)d_in[4];
  const float* headb = (const float*)d_in[5];
  const float* tailW = (const float*)d_in[6];
  const float* tailb = (const float*)d_in[7];
  const float* bilW  = (const float*)d_in[8];
  const float* bilb  = (const float*)d_in[9];
  const int*   mpos  = (const int*)d_in[10];
  const int*   hts   = (const int*)d_in[11];
  float* out = (float*)d_out;

  float* ws      = (float*)d_ws;
  float* ent_att = ws;                    // 1,179,648 f
  float* ht_att  = ent_att + 1179648;     // 2,260,992 f
  float* rs_f    = ht_att  + 2260992;     // 1,695,744 f
  float* ment    = rs_f    + 1695744;     //   294,912 f
  float* kment   = ment    + 294912;      //   294,912 f
  float* q_c     = kment   + 294912;      // 1,695,744 f
  float* h_ent   = q_c     + 1695744;     // 1,695,744 f
  float* t_ent   = h_ent   + 1695744;     // 1,695,744 f
  float* hsb     = t_ent   + 1695744;     // 1,695,744 f
  float* tsb     = hsb     + 1695744;     // 1,695,744 f  -> total 14,204,928 f = 56.8 MB
  float* partial = ws;                    // reuse ent_att+ht_att region (dead after k_rs):
                                          // 12*2208*97 = 2,570,112 <= 3,440,640 ok

  k_ent_att<<<Bc*Ec*Hc, 256, 0, stream>>>(att, mpos, ent_att);
  k_ht_att <<<Rc, 256, 0, stream>>>(ent_att, hts, ht_att);
  k_rs     <<<Bc*(Pc/8), 256, 0, stream>>>(seq, ht_att, rs_f);
  k_gather <<<(Bc*Ec*Mc*Dc)/256, 256, 0, stream>>>(seq, mpos, ment);
  k_rowgemm<768,false><<<(Bc*Ec*Mc)/8, 256, 0, stream>>>(ment, nullptr, W_k, nullptr, kment);
  k_rowgemm<768,false><<<Rc/8, 256, 0, stream>>>(rs_f, nullptr, W_q, nullptr, q_c);
  k_pool   <<<Rc, 256, 0, stream>>>(kment, ment, q_c, hts, h_ent, t_ent);
  k_rowgemm<1536,true><<<Rc/8, 256, 0, stream>>>(h_ent, rs_f, headW, headb, hsb);
  k_rowgemm<1536,true><<<Rc/8, 256, 0, stream>>>(t_ent, rs_f, tailW, tailb, tsb);
  k_bilinear<<<(Rc/32)*KSPLIT, 256, 0, stream>>>(hsb, tsb, bilW, partial);
  k_reduce <<<(Rc*NLc+255)/256, 256, 0, stream>>>(partial, bilb, out);
}

// Round 2
// 673.115 us; speedup vs baseline: 2.0243x; 2.0243x over previous
//
#include <hip/hip_runtime.h>
#include <hip/hip_bf16.h>
#include <math.h>

#define Bc 4
#define Lc 1024
#define Dc 768
#define Hc 12
#define Ec 24
#define Mc 4
#define Pc 552
#define EMBc 768
#define NLc 97
#define Rc (Bc*Pc)      // 2208
#define KSPL 48         // 12 k-blocks x 4 splits of i

typedef __attribute__((ext_vector_type(4))) float f32x4;
typedef __attribute__((ext_vector_type(8))) short short8;

static __device__ __forceinline__ unsigned short f2bf(float x){
  unsigned int u = __float_as_uint(x);
  unsigned int r = u + 0x7fffu + ((u >> 16) & 1u);   // RNE
  return (unsigned short)(r >> 16);
}

// K1: ent_att[b,e,h,l] = mean_m attention[b,h,pos[b,e,m],l]
__global__ __launch_bounds__(256) void k_ent_att(const float* __restrict__ att,
                                                 const int* __restrict__ mpos,
                                                 float* __restrict__ ent_att){
  int blk = blockIdx.x;             // (b*E+e)*H + h
  int h  = blk % Hc;
  int be = blk / Hc;
  int b  = be / Ec;
  int p0 = mpos[be*Mc+0]+1, p1 = mpos[be*Mc+1]+1;
  int p2 = mpos[be*Mc+2]+1, p3 = mpos[be*Mc+3]+1;
  const float* ab = att + ((size_t)b*Hc + h)*Lc*Lc;
  const float* a0 = ab + (size_t)p0*Lc;
  const float* a1 = ab + (size_t)p1*Lc;
  const float* a2 = ab + (size_t)p2*Lc;
  const float* a3 = ab + (size_t)p3*Lc;
  float* o = ent_att + (size_t)blk*Lc;
  for (int l = threadIdx.x; l < Lc; l += 256)
    o[l] = 0.25f*(a0[l]+a1[l]+a2[l]+a3[l]);
}

// K2: ht_att[b,p,l] = normalize_l( mean_h ent_att[b,h_idx,h,l]*ent_att[b,t_idx,h,l] )
__global__ __launch_bounds__(256) void k_ht_att(const float* __restrict__ ent_att,
                                                const int* __restrict__ hts,
                                                float* __restrict__ ht_att){
  int r = blockIdx.x;
  int b = r / Pc;
  int hi = hts[r*2+0], ti = hts[r*2+1];
  const float* eh = ent_att + (size_t)(b*Ec+hi)*Hc*Lc;
  const float* et = ent_att + (size_t)(b*Ec+ti)*Hc*Lc;
  __shared__ float raw[Lc];
  __shared__ float wsum[4];
  float lsum = 0.f;
  for (int l = threadIdx.x; l < Lc; l += 256){
    float s = 0.f;
    #pragma unroll
    for (int h = 0; h < Hc; h++) s += eh[h*Lc+l]*et[h*Lc+l];
    s *= (1.0f/Hc);
    raw[l] = s;
    lsum += s;
  }
  for (int off = 32; off; off >>= 1) lsum += __shfl_down(lsum, off);
  if ((threadIdx.x & 63) == 0) wsum[threadIdx.x>>6] = lsum;
  __syncthreads();
  float inv = 1.0f/(wsum[0]+wsum[1]+wsum[2]+wsum[3] + 1e-5f);
  float* o = ht_att + (size_t)r*Lc;
  for (int l = threadIdx.x; l < Lc; l += 256)
    o[l] = raw[l]*inv;
}

// K3: rs[b,p,d] = sum_l ht_att[b,p,l]*seq[b,l,d]; N-split x3 for occupancy
__global__ __launch_bounds__(256) void k_rs(const float* __restrict__ seq,
                                            const float* __restrict__ ht_att,
                                            float* __restrict__ rs_f){
  int bx = blockIdx.x;
  int nseg = bx % 3; int t2 = bx / 3;
  int b  = t2 / (Pc/8);
  int pt = t2 % (Pc/8);
  int p0 = pt*8;
  __shared__ float ht[Lc][8];     // 32 KB, transposed for float4 broadcast reads
  for (int idx = threadIdx.x; idx < 8*Lc; idx += 256){
    int pp = idx >> 10, l = idx & (Lc-1);
    ht[l][pp] = ht_att[((size_t)(b*Pc + p0 + pp))*Lc + l];
  }
  __syncthreads();
  int d0 = nseg*256 + threadIdx.x;
  const float* sb = seq + (size_t)b*Lc*Dc + d0;
  float acc[8] = {};
  for (int l = 0; l < Lc; l++){
    float s = sb[(size_t)l*Dc];
    float4 h0 = *(const float4*)&ht[l][0];
    float4 h1 = *(const float4*)&ht[l][4];
    acc[0]=fmaf(h0.x,s,acc[0]); acc[1]=fmaf(h0.y,s,acc[1]);
    acc[2]=fmaf(h0.z,s,acc[2]); acc[3]=fmaf(h0.w,s,acc[3]);
    acc[4]=fmaf(h1.x,s,acc[4]); acc[5]=fmaf(h1.y,s,acc[5]);
    acc[6]=fmaf(h1.z,s,acc[6]); acc[7]=fmaf(h1.w,s,acc[7]);
  }
  #pragma unroll
  for (int pp = 0; pp < 8; pp++)
    rs_f[((size_t)(b*Pc + p0 + pp))*Dc + d0] = acc[pp];
}

// K4a: gather 384 distinct mention embeddings
__global__ __launch_bounds__(256) void k_gather(const float* __restrict__ seq,
                                                const int* __restrict__ mpos,
                                                float* __restrict__ ment){
  int idx = blockIdx.x*256 + threadIdx.x;
  int d = idx % Dc;
  int bem = idx / Dc;
  int b = bem / (Ec*Mc);
  int pos = mpos[bem] + 1;
  ment[idx] = seq[((size_t)b*Lc + pos)*Dc + d];
}

// Row-tiled GEMM, N-split x3: C[r, d0] = op(concat(A1,A2)[r] @ W + b)
template<int KDIM, bool TANH>
__global__ __launch_bounds__(256) void k_rowgemm(const float* __restrict__ A1,
                                                 const float* __restrict__ A2,
                                                 const float* __restrict__ W,
                                                 const float* __restrict__ bias,
                                                 float* __restrict__ C){
  __shared__ float a[8][KDIM];
  int rblk = blockIdx.x / 3, nseg = blockIdx.x % 3;
  int r0 = rblk*8;
  for (int idx = threadIdx.x; idx < 8*KDIM; idx += 256){
    int rr = idx / KDIM, k = idx % KDIM;
    a[rr][k] = (k < Dc) ? A1[(size_t)(r0+rr)*Dc + k]
                        : A2[(size_t)(r0+rr)*Dc + k - Dc];
  }
  __syncthreads();
  int d0 = nseg*256 + threadIdx.x;
  float acc[8] = {};
  for (int kq = 0; kq < KDIM; kq += 4){
    float w0 = W[(size_t)(kq+0)*Dc + d0];
    float w1 = W[(size_t)(kq+1)*Dc + d0];
    float w2 = W[(size_t)(kq+2)*Dc + d0];
    float w3 = W[(size_t)(kq+3)*Dc + d0];
    #pragma unroll
    for (int rr = 0; rr < 8; rr++){
      float4 av = *(const float4*)&a[rr][kq];
      acc[rr] = fmaf(av.x,w0,fmaf(av.y,w1,fmaf(av.z,w2,fmaf(av.w,w3,acc[rr]))));
    }
  }
  #pragma unroll
  for (int rr = 0; rr < 8; rr++){
    float o0 = acc[rr];
    if (bias) o0 += bias[d0];
    if (TANH) o0 = tanhf(o0);
    C[(size_t)(r0+rr)*Dc + d0] = o0;
  }
}

// K6: scores -> softmax over M=4 -> weighted mention sum, both sides
__global__ __launch_bounds__(256) void k_pool(const float* __restrict__ kment,
                                              const float* __restrict__ ment,
                                              const float* __restrict__ q_c,
                                              const int* __restrict__ hts,
                                              float* __restrict__ h_ent,
                                              float* __restrict__ t_ent){
  int r = blockIdx.x;
  int b = r / Pc;
  __shared__ float q[Dc];
  __shared__ float sred[16];
  __shared__ float sw[Mc];
  for (int d = threadIdx.x; d < Dc; d += 256) q[d] = q_c[(size_t)r*Dc + d];
  __syncthreads();
  const float invs = 0.03608439182435161f;  // 1/sqrt(768)
  for (int side = 0; side < 2; side++){
    int e = hts[r*2+side];
    const float* kb = kment + (size_t)(b*Ec+e)*Mc*Dc;
    const float* mb = ment  + (size_t)(b*Ec+e)*Mc*Dc;
    float part[Mc] = {0.f,0.f,0.f,0.f};
    for (int d = threadIdx.x; d < Dc; d += 256){
      float qv = q[d];
      #pragma unroll
      for (int m = 0; m < Mc; m++) part[m] = fmaf(kb[m*Dc+d], qv, part[m]);
    }
    #pragma unroll
    for (int m = 0; m < Mc; m++)
      for (int off = 32; off; off >>= 1) part[m] += __shfl_down(part[m], off);
    if ((threadIdx.x & 63) == 0){
      int w = threadIdx.x >> 6;
      #pragma unroll
      for (int m = 0; m < Mc; m++) sred[w*4+m] = part[m];
    }
    __syncthreads();
    if (threadIdx.x == 0){
      float sc[Mc]; float mx = -1e30f;
      for (int m = 0; m < Mc; m++){
        sc[m] = (sred[m]+sred[4+m]+sred[8+m]+sred[12+m])*invs;
        mx = fmaxf(mx, sc[m]);
      }
      float ssum = 0.f;
      for (int m = 0; m < Mc; m++){ sc[m] = expf(sc[m]-mx); ssum += sc[m]; }
      float isum = 1.0f/ssum;
      for (int m = 0; m < Mc; m++) sw[m] = sc[m]*isum;
    }
    __syncthreads();
    float w0 = sw[0], w1 = sw[1], w2 = sw[2], w3 = sw[3];
    float* o = (side ? t_ent : h_ent) + (size_t)r*Dc;
    for (int d = threadIdx.x; d < Dc; d += 256)
      o[d] = w0*mb[d] + w1*mb[Dc+d] + w2*mb[2*Dc+d] + w3*mb[3*Dc+d];
    __syncthreads();
  }
}

// K7: W fp32 -> bf16, layout [chunk=1536][n=112][kk=40(pad, 32 used)]
__global__ __launch_bounds__(256) void k_wconv(const float* __restrict__ W,
                                               unsigned short* __restrict__ Wbf){
  int ch = blockIdx.x;
  const float* Ws = W + (size_t)ch*32*NLc;
  unsigned short* o = Wbf + (size_t)ch*4480;
  for (int idx = threadIdx.x; idx < 112*32; idx += 256){
    int n = idx % 112, kk = idx / 112;      // consecutive threads -> consecutive n (coalesced read)
    float v = (n < NLc) ? Ws[(size_t)kk*NLc + n] : 0.f;
    o[n*40 + kk] = f2bf(v);
  }
}

// K8: MFMA bilinear. out = sum_{k,i,j} hs[r,k*64+i]*ts[r,k*64+j]*W[(k*64+i)*64+j, n]
// grid = 18 M-blocks x 48 k-splits; block = 4 waves; BM=128 (wave: 2 M-tiles x 7 N-tiles)
__global__ __launch_bounds__(256) void k_bilinear_mfma(
    const float* __restrict__ hs, const float* __restrict__ ts,
    const unsigned short* __restrict__ Wbf,
    float* __restrict__ partial)
{
  int mb = blockIdx.x / KSPL;
  int kb = blockIdx.x % KSPL;
  int k  = kb >> 2;             // EMB block 0..11
  int i0 = (kb & 3) * 16;       // i sub-range

  int tid  = threadIdx.x;
  int lane = tid & 63;
  int wid  = tid >> 6;
  int row16 = lane & 15;
  int oct   = lane >> 4;

  int rbase = mb*128 + wid*32;

  __shared__ __align__(16) unsigned short Wlds[2][4480];  // [112][40] bf16, double-buffered

  // ---- register preload of hs/ts (fp32, once per block) ----
  float4 tsr[2][2][2];   // [m][jhalf][q]: ts[r_m][k*64 + jhalf*32 + oct*8 + q*4 + e]
  float4 hsr[2][4];      // [m][q]: hs[r_m][k*64 + i0 + q*4 + e]
  #pragma unroll
  for (int m = 0; m < 2; m++){
    int r = rbase + m*16 + row16; if (r > Rc-1) r = Rc-1;
    const float* tp = ts + (size_t)r*EMBc + k*64;
    tsr[m][0][0] = *(const float4*)(tp + oct*8);
    tsr[m][0][1] = *(const float4*)(tp + oct*8 + 4);
    tsr[m][1][0] = *(const float4*)(tp + 32 + oct*8);
    tsr[m][1][1] = *(const float4*)(tp + 32 + oct*8 + 4);
    const float* hp = hs + (size_t)r*EMBc + k*64 + i0;
    hsr[m][0] = *(const float4*)(hp + 0);
    hsr[m][1] = *(const float4*)(hp + 4);
    hsr[m][2] = *(const float4*)(hp + 8);
    hsr[m][3] = *(const float4*)(hp + 12);
  }

  const char* wsrc = (const char*)(Wbf + ((size_t)k*128 + (size_t)(kb&3)*32) * 4480);

  // stage chunk 0 -> buf 0   (8960 B = 560 x 16B units)
  #pragma unroll
  for (int rr = 0; rr < 3; rr++){
    int u = tid + rr*256;
    if (u < 560)
      __builtin_amdgcn_global_load_lds(
        (const __attribute__((address_space(1))) unsigned int*)(wsrc + (size_t)u*16),
        (__attribute__((address_space(3))) unsigned int*)((char*)&Wlds[0][0] + u*16),
        16, 0, 0);
  }

  f32x4 acc[2][7];
  #pragma unroll
  for (int m = 0; m < 2; m++)
    #pragma unroll
    for (int n = 0; n < 7; n++)
      acc[m][n] = (f32x4){0.f,0.f,0.f,0.f};

  __syncthreads();   // drains vmcnt -> chunk 0 staged

  #pragma unroll
  for (int c = 0; c < 32; c++){
    int cur = c & 1;
    if (c < 31){
      const char* nsrc = wsrc + (size_t)(c+1)*8960;
      #pragma unroll
      for (int rr = 0; rr < 3; rr++){
        int u = tid + rr*256;
        if (u < 560)
          __builtin_amdgcn_global_load_lds(
            (const __attribute__((address_space(1))) unsigned int*)(nsrc + (size_t)u*16),
            (__attribute__((address_space(3))) unsigned int*)((char*)&Wlds[cur^1][0] + u*16),
            16, 0, 0);
      }
    }
    // A-fragments from registers: bl[r][kk] = hs[r][i]*ts[r][jb + kk]
    const int ci = c >> 1, cj = c & 1;
    short8 af[2];
    #pragma unroll
    for (int m = 0; m < 2; m++){
      float hv = ((const float*)&hsr[m][ci>>2])[ci&3];
      float4 t0 = tsr[m][cj][0];
      float4 t1 = tsr[m][cj][1];
      af[m][0] = (short)f2bf(hv*t0.x);
      af[m][1] = (short)f2bf(hv*t0.y);
      af[m][2] = (short)f2bf(hv*t0.z);
      af[m][3] = (short)f2bf(hv*t0.w);
      af[m][4] = (short)f2bf(hv*t1.x);
      af[m][5] = (short)f2bf(hv*t1.y);
      af[m][6] = (short)f2bf(hv*t1.z);
      af[m][7] = (short)f2bf(hv*t1.w);
    }
    #pragma unroll
    for (int n = 0; n < 7; n++){
      short8 bfr = *(const short8*)&Wlds[cur][(n*16 + row16)*40 + oct*8];
      acc[0][n] = __builtin_amdgcn_mfma_f32_16x16x32_bf16(af[0], bfr, acc[0][n], 0, 0, 0);
      acc[1][n] = __builtin_amdgcn_mfma_f32_16x16x32_bf16(af[1], bfr, acc[1][n], 0, 0, 0);
    }
    __syncthreads();   // reads of buf[cur] done + stage of buf[cur^1] drained
  }

  // store partials: D layout col=lane&15, row=(lane>>4)*4+j  [m89-verified]
  float* pk = partial + (size_t)kb*Rc*NLc;
  #pragma unroll
  for (int m = 0; m < 2; m++){
    #pragma unroll
    for (int n = 0; n < 7; n++){
      #pragma unroll
      for (int j = 0; j < 4; j++){
        int r = rbase + m*16 + oct*4 + j;
        int col = n*16 + row16;
        if (r < Rc && col < NLc)
          pk[(size_t)r*NLc + col] = acc[m][n][j];
      }
    }
  }
}

// K9: sum partials + bias
__global__ __launch_bounds__(256) void k_reduce(const float* __restrict__ partial,
                                                const float* __restrict__ bilb,
                                                float* __restrict__ out){
  int idx = blockIdx.x*256 + threadIdx.x;
  if (idx >= Rc*NLc) return;
  int n = idx % NLc;
  float s = bilb[n];
  #pragma unroll
  for (int ks = 0; ks < KSPL; ks++) s += partial[(size_t)ks*Rc*NLc + idx];
  out[idx] = s;
}

extern "C" void kernel_launch(void* const* d_in, const int* in_sizes, int n_in,
                              void* d_out, int out_size, void* d_ws, size_t ws_size,
                              hipStream_t stream){
  const float* seq   = (const float*)d_in[0];
  const float* att   = (const float*)d_in[1];
  const float* W_q   = (const float*)d_in[2];
  const float* W_k   = (const float*)d_in[3];
  const float* headW = (const float*)d_in[4];
  const float* headb = (const float*)d_in[5];
  const float* tailW = (const float*)d_in[6];
  const float* tailb = (const float*)d_in[7];
  const float* bilW  = (const float*)d_in[8];
  const float* bilb  = (const float*)d_in[9];
  const int*   mpos  = (const int*)d_in[10];
  const int*   hts   = (const int*)d_in[11];
  float* out = (float*)d_out;

  float* ws      = (float*)d_ws;
  float* ent_att = ws;                    // 1,179,648 f
  float* ht_att  = ent_att + 1179648;     // 2,260,992 f
  float* rs_f    = ht_att  + 2260992;     // 1,695,744 f
  float* ment    = rs_f    + 1695744;     //   294,912 f
  float* kment   = ment    + 294912;      //   294,912 f
  float* q_c     = kment   + 294912;      // 1,695,744 f
  float* h_ent   = q_c     + 1695744;     // 1,695,744 f
  float* t_ent   = h_ent   + 1695744;     // 1,695,744 f
  float* hsb     = t_ent   + 1695744;     // 1,695,744 f
  float* tsb     = hsb     + 1695744;     // 1,695,744 f
  unsigned short* Wbf = (unsigned short*)(tsb + 1695744);  // 6,881,280 u16 (13.76 MB)
  // partial overlaps [ent_att .. t_ent] (all dead before bilinear): 48*2208*97 = 10,280,448 f
  float* partial = ws;

  k_wconv  <<<1536, 256, 0, stream>>>(bilW, Wbf);
  k_ent_att<<<Bc*Ec*Hc, 256, 0, stream>>>(att, mpos, ent_att);
  k_ht_att <<<Rc, 256, 0, stream>>>(ent_att, hts, ht_att);
  k_rs     <<<Bc*(Pc/8)*3, 256, 0, stream>>>(seq, ht_att, rs_f);
  k_gather <<<(Bc*Ec*Mc*Dc)/256, 256, 0, stream>>>(seq, mpos, ment);
  k_rowgemm<768,false><<<((Bc*Ec*Mc)/8)*3, 256, 0, stream>>>(ment, nullptr, W_k, nullptr, kment);
  k_rowgemm<768,false><<<(Rc/8)*3, 256, 0, stream>>>(rs_f, nullptr, W_q, nullptr, q_c);
  k_pool   <<<Rc, 256, 0, stream>>>(kment, ment, q_c, hts, h_ent, t_ent);
  k_rowgemm<1536,true><<<(Rc/8)*3, 256, 0, stream>>>(h_ent, rs_f, headW, headb, hsb);
  k_rowgemm<1536,true><<<(Rc/8)*3, 256, 0, stream>>>(t_ent, rs_f, tailW, tailb, tsb);
  k_bilinear_mfma<<<18*KSPL, 256, 0, stream>>>(hsb, tsb, Wbf, partial);
  k_reduce <<<(Rc*NLc+255)/256, 256, 0, stream>>>(partial, bilb, out);
}

// Round 3
// 326.259 us; speedup vs baseline: 4.1763x; 2.0631x over previous
//
#include <hip/hip_runtime.h>
#include <hip/hip_bf16.h>
#include <math.h>

#define Bc 4
#define Lc 1024
#define Dc 768
#define Hc 12
#define Ec 24
#define Mc 4
#define Pc 552
#define EMBc 768
#define NLc 97
#define Rc (Bc*Pc)      // 2208
#define KSPL 48         // bilinear: 12 k-blocks x 4 splits of i

typedef __attribute__((ext_vector_type(4))) float f32x4;
typedef __attribute__((ext_vector_type(8))) short short8;

static __device__ __forceinline__ unsigned short f2bf(float x){
  unsigned int u = __float_as_uint(x);
  unsigned int r = u + 0x7fffu + ((u >> 16) & 1u);   // RNE
  return (unsigned short)(r >> 16);
}

// K1: ent_att[b,e,h,l] = mean_m attention[b,h,pos[b,e,m],l]
__global__ __launch_bounds__(256) void k_ent_att(const float* __restrict__ att,
                                                 const int* __restrict__ mpos,
                                                 float* __restrict__ ent_att){
  int blk = blockIdx.x;             // (b*E+e)*H + h
  int h  = blk % Hc;
  int be = blk / Hc;
  int b  = be / Ec;
  int p0 = mpos[be*Mc+0]+1, p1 = mpos[be*Mc+1]+1;
  int p2 = mpos[be*Mc+2]+1, p3 = mpos[be*Mc+3]+1;
  const float* ab = att + ((size_t)b*Hc + h)*Lc*Lc;
  const float* a0 = ab + (size_t)p0*Lc;
  const float* a1 = ab + (size_t)p1*Lc;
  const float* a2 = ab + (size_t)p2*Lc;
  const float* a3 = ab + (size_t)p3*Lc;
  float* o = ent_att + (size_t)blk*Lc;
  for (int l = threadIdx.x; l < Lc; l += 256)
    o[l] = 0.25f*(a0[l]+a1[l]+a2[l]+a3[l]);
}

// K2: ht_att -> bf16 htbf[r][l]
__global__ __launch_bounds__(256) void k_ht_att(const float* __restrict__ ent_att,
                                                const int* __restrict__ hts,
                                                unsigned short* __restrict__ htbf){
  int r = blockIdx.x;
  int b = r / Pc;
  int hi = hts[r*2+0], ti = hts[r*2+1];
  const float* eh = ent_att + (size_t)(b*Ec+hi)*Hc*Lc;
  const float* et = ent_att + (size_t)(b*Ec+ti)*Hc*Lc;
  __shared__ float raw[Lc];
  __shared__ float wsum[4];
  float lsum = 0.f;
  for (int l = threadIdx.x; l < Lc; l += 256){
    float s = 0.f;
    #pragma unroll
    for (int h = 0; h < Hc; h++) s += eh[h*Lc+l]*et[h*Lc+l];
    s *= (1.0f/Hc);
    raw[l] = s;
    lsum += s;
  }
  for (int off = 32; off; off >>= 1) lsum += __shfl_down(lsum, off);
  if ((threadIdx.x & 63) == 0) wsum[threadIdx.x>>6] = lsum;
  __syncthreads();
  float inv = 1.0f/(wsum[0]+wsum[1]+wsum[2]+wsum[3] + 1e-5f);
  unsigned short* o = htbf + (size_t)r*Lc;
  for (int l = threadIdx.x; l < Lc; l += 256)
    o[l] = f2bf(raw[l]*inv);
}

// transpose + fp32->bf16: dst[c][r] = src[r][c]; grid (rows/64, cols/64, nb)
__global__ __launch_bounds__(256) void k_tcvt(const float* __restrict__ src,
                                              unsigned short* __restrict__ dst,
                                              int rows, int cols,
                                              size_t sbs, size_t dbs){
  int b = blockIdx.z;
  src += (size_t)b*sbs; dst += (size_t)b*dbs;
  int r0 = blockIdx.x*64, c0 = blockIdx.y*64;
  __shared__ float t[64][65];
  #pragma unroll
  for (int q = 0; q < 16; q++){
    int idx = q*256 + threadIdx.x;
    int rr = idx >> 6, cc = idx & 63;
    t[rr][cc] = src[(size_t)(r0+rr)*cols + c0+cc];
  }
  __syncthreads();
  #pragma unroll
  for (int q = 0; q < 16; q++){
    int idx = q*256 + threadIdx.x;
    int cc = idx >> 6, rr = idx & 63;
    dst[(size_t)(c0+cc)*rows + r0+rr] = f2bf(t[rr][cc]);
  }
}

// K3 (MFMA): rs_bf[b][p][d] = sum_l htbf[b*552+p][l]*seqt[b][d][l]
__global__ __launch_bounds__(256) void k_rs_mfma(const unsigned short* __restrict__ htbf,
                                                 const unsigned short* __restrict__ seqt,
                                                 unsigned short* __restrict__ rs_bf){
  int b = blockIdx.z;
  const unsigned short* A = htbf + (size_t)b*Pc*Lc;
  const unsigned short* Wt = seqt + (size_t)b*Dc*Lc;
  unsigned short* C = rs_bf + (size_t)b*Pc*Dc;
  int lane = threadIdx.x & 63, wid = threadIdx.x >> 6;
  int row16 = lane & 15, oct = lane >> 4;
  int rbase = blockIdx.x*128 + wid*32;
  int r0 = rbase + row16;      if (r0 > Pc-1) r0 = Pc-1;
  int r1 = rbase + 16 + row16; if (r1 > Pc-1) r1 = Pc-1;
  const unsigned short* a0p = A + (size_t)r0*Lc + oct*8;
  const unsigned short* a1p = A + (size_t)r1*Lc + oct*8;
  const unsigned short* wp  = Wt + (size_t)(blockIdx.y*64 + row16)*Lc + oct*8;
  f32x4 acc[2][4];
  #pragma unroll
  for (int m = 0; m < 2; m++)
    #pragma unroll
    for (int n = 0; n < 4; n++) acc[m][n] = (f32x4){0.f,0.f,0.f,0.f};
  #pragma unroll 4
  for (int kc = 0; kc < Lc; kc += 32){
    short8 a0 = *(const short8*)(a0p + kc);
    short8 a1 = *(const short8*)(a1p + kc);
    #pragma unroll
    for (int n = 0; n < 4; n++){
      short8 bv = *(const short8*)(wp + (size_t)n*16*Lc + kc);
      acc[0][n] = __builtin_amdgcn_mfma_f32_16x16x32_bf16(a0, bv, acc[0][n], 0, 0, 0);
      acc[1][n] = __builtin_amdgcn_mfma_f32_16x16x32_bf16(a1, bv, acc[1][n], 0, 0, 0);
    }
  }
  #pragma unroll
  for (int m = 0; m < 2; m++)
    #pragma unroll
    for (int n = 0; n < 4; n++)
      #pragma unroll
      for (int j = 0; j < 4; j++){
        int r = rbase + m*16 + oct*4 + j;
        if (r < Pc){
          int col = blockIdx.y*64 + n*16 + row16;
          C[(size_t)r*Dc + col] = f2bf(acc[m][n][j]);
        }
      }
}

// K4a: gather 384 distinct mention embeddings (fp32 + bf16)
__global__ __launch_bounds__(256) void k_gather(const float* __restrict__ seq,
                                                const int* __restrict__ mpos,
                                                float* __restrict__ ment,
                                                unsigned short* __restrict__ ment_bf){
  int idx = blockIdx.x*256 + threadIdx.x;
  int d = idx % Dc;
  int bem = idx / Dc;
  int b = bem / (Ec*Mc);
  int pos = mpos[bem] + 1;
  float v = seq[((size_t)b*Lc + pos)*Dc + d];
  ment[idx] = v;
  ment_bf[idx] = f2bf(v);
}

// Generic MFMA GEMM: C[M,768] = op( [A1 | A2] @ Wt^T + bias )
// A1,A2: bf16 [M][768] each (A2 optional, K2=0 or 768); Wt: bf16 [768][768+K2]
__global__ __launch_bounds__(256) void k_gemm(const unsigned short* __restrict__ A1,
                                              const unsigned short* __restrict__ A2,
                                              const int K2,
                                              const unsigned short* __restrict__ Wt,
                                              const float* __restrict__ bias,
                                              float* __restrict__ C,
                                              const int M, const int do_tanh){
  const int Ktot = Dc + K2;
  int lane = threadIdx.x & 63, wid = threadIdx.x >> 6;
  int row16 = lane & 15, oct = lane >> 4;
  int rbase = blockIdx.x*128 + wid*32;
  int r0 = rbase + row16;      if (r0 > M-1) r0 = M-1;
  int r1 = rbase + 16 + row16; if (r1 > M-1) r1 = M-1;
  const unsigned short* a0p = A1 + (size_t)r0*Dc + oct*8;
  const unsigned short* a1p = A1 + (size_t)r1*Dc + oct*8;
  const unsigned short* wp  = Wt + (size_t)(blockIdx.y*64 + row16)*Ktot + oct*8;
  f32x4 acc[2][4];
  #pragma unroll
  for (int m = 0; m < 2; m++)
    #pragma unroll
    for (int n = 0; n < 4; n++) acc[m][n] = (f32x4){0.f,0.f,0.f,0.f};
  #pragma unroll 4
  for (int kc = 0; kc < Dc; kc += 32){
    short8 a0 = *(const short8*)(a0p + kc);
    short8 a1 = *(const short8*)(a1p + kc);
    #pragma unroll
    for (int n = 0; n < 4; n++){
      short8 bv = *(const short8*)(wp + (size_t)n*16*Ktot + kc);
      acc[0][n] = __builtin_amdgcn_mfma_f32_16x16x32_bf16(a0, bv, acc[0][n], 0, 0, 0);
      acc[1][n] = __builtin_amdgcn_mfma_f32_16x16x32_bf16(a1, bv, acc[1][n], 0, 0, 0);
    }
  }
  if (K2 > 0){
    const unsigned short* b0p = A2 + (size_t)r0*Dc + oct*8;
    const unsigned short* b1p = A2 + (size_t)r1*Dc + oct*8;
    const unsigned short* wp2 = wp + Dc;
    #pragma unroll 4
    for (int kc = 0; kc < Dc; kc += 32){
      short8 a0 = *(const short8*)(b0p + kc);
      short8 a1 = *(const short8*)(b1p + kc);
      #pragma unroll
      for (int n = 0; n < 4; n++){
        short8 bv = *(const short8*)(wp2 + (size_t)n*16*Ktot + kc);
        acc[0][n] = __builtin_amdgcn_mfma_f32_16x16x32_bf16(a0, bv, acc[0][n], 0, 0, 0);
        acc[1][n] = __builtin_amdgcn_mfma_f32_16x16x32_bf16(a1, bv, acc[1][n], 0, 0, 0);
      }
    }
  }
  #pragma unroll
  for (int m = 0; m < 2; m++)
    #pragma unroll
    for (int n = 0; n < 4; n++)
      #pragma unroll
      for (int j = 0; j < 4; j++){
        int r = rbase + m*16 + oct*4 + j;
        if (r < M){
          int col = blockIdx.y*64 + n*16 + row16;
          float v = acc[m][n][j];
          if (bias) v += bias[col];
          if (do_tanh) v = tanhf(v);
          C[(size_t)r*Dc + col] = v;
        }
      }
}

// K6: scores -> softmax over M=4 -> weighted mention sum -> bf16
__global__ __launch_bounds__(256) void k_pool(const float* __restrict__ kment,
                                              const float* __restrict__ ment,
                                              const float* __restrict__ q_c,
                                              const int* __restrict__ hts,
                                              unsigned short* __restrict__ h_bf,
                                              unsigned short* __restrict__ t_bf){
  int r = blockIdx.x;
  int b = r / Pc;
  __shared__ float q[Dc];
  __shared__ float sred[16];
  __shared__ float sw[Mc];
  for (int d = threadIdx.x; d < Dc; d += 256) q[d] = q_c[(size_t)r*Dc + d];
  __syncthreads();
  const float invs = 0.03608439182435161f;  // 1/sqrt(768)
  for (int side = 0; side < 2; side++){
    int e = hts[r*2+side];
    const float* kb = kment + (size_t)(b*Ec+e)*Mc*Dc;
    const float* mb = ment  + (size_t)(b*Ec+e)*Mc*Dc;
    float part[Mc] = {0.f,0.f,0.f,0.f};
    for (int d = threadIdx.x; d < Dc; d += 256){
      float qv = q[d];
      #pragma unroll
      for (int m = 0; m < Mc; m++) part[m] = fmaf(kb[m*Dc+d], qv, part[m]);
    }
    #pragma unroll
    for (int m = 0; m < Mc; m++)
      for (int off = 32; off; off >>= 1) part[m] += __shfl_down(part[m], off);
    if ((threadIdx.x & 63) == 0){
      int w = threadIdx.x >> 6;
      #pragma unroll
      for (int m = 0; m < Mc; m++) sred[w*4+m] = part[m];
    }
    __syncthreads();
    if (threadIdx.x == 0){
      float sc[Mc]; float mx = -1e30f;
      for (int m = 0; m < Mc; m++){
        sc[m] = (sred[m]+sred[4+m]+sred[8+m]+sred[12+m])*invs;
        mx = fmaxf(mx, sc[m]);
      }
      float ssum = 0.f;
      for (int m = 0; m < Mc; m++){ sc[m] = expf(sc[m]-mx); ssum += sc[m]; }
      float isum = 1.0f/ssum;
      for (int m = 0; m < Mc; m++) sw[m] = sc[m]*isum;
    }
    __syncthreads();
    float w0 = sw[0], w1 = sw[1], w2 = sw[2], w3 = sw[3];
    unsigned short* o = (side ? t_bf : h_bf) + (size_t)r*Dc;
    for (int d = threadIdx.x; d < Dc; d += 256)
      o[d] = f2bf(w0*mb[d] + w1*mb[Dc+d] + w2*mb[2*Dc+d] + w3*mb[3*Dc+d]);
    __syncthreads();
  }
}

// K7: bilinear W fp32 -> bf16, layout [chunk=1536][n=112][kk=40(pad, 32 used)]
__global__ __launch_bounds__(256) void k_wconv(const float* __restrict__ W,
                                               unsigned short* __restrict__ Wbf){
  int ch = blockIdx.x;
  const float* Ws = W + (size_t)ch*32*NLc;
  unsigned short* o = Wbf + (size_t)ch*4480;
  for (int idx = threadIdx.x; idx < 112*32; idx += 256){
    int n = idx % 112, kk = idx / 112;
    float v = (n < NLc) ? Ws[(size_t)kk*NLc + n] : 0.f;
    o[n*40 + kk] = f2bf(v);
  }
}

// K8: MFMA bilinear (unchanged from round 2)
__global__ __launch_bounds__(256) void k_bilinear_mfma(
    const float* __restrict__ hs, const float* __restrict__ ts,
    const unsigned short* __restrict__ Wbf,
    float* __restrict__ partial)
{
  int mb = blockIdx.x / KSPL;
  int kb = blockIdx.x % KSPL;
  int k  = kb >> 2;
  int i0 = (kb & 3) * 16;

  int tid  = threadIdx.x;
  int lane = tid & 63;
  int wid  = tid >> 6;
  int row16 = lane & 15;
  int oct   = lane >> 4;

  int rbase = mb*128 + wid*32;

  __shared__ __align__(16) unsigned short Wlds[2][4480];

  float4 tsr[2][2][2];
  float4 hsr[2][4];
  #pragma unroll
  for (int m = 0; m < 2; m++){
    int r = rbase + m*16 + row16; if (r > Rc-1) r = Rc-1;
    const float* tp = ts + (size_t)r*EMBc + k*64;
    tsr[m][0][0] = *(const float4*)(tp + oct*8);
    tsr[m][0][1] = *(const float4*)(tp + oct*8 + 4);
    tsr[m][1][0] = *(const float4*)(tp + 32 + oct*8);
    tsr[m][1][1] = *(const float4*)(tp + 32 + oct*8 + 4);
    const float* hp = hs + (size_t)r*EMBc + k*64 + i0;
    hsr[m][0] = *(const float4*)(hp + 0);
    hsr[m][1] = *(const float4*)(hp + 4);
    hsr[m][2] = *(const float4*)(hp + 8);
    hsr[m][3] = *(const float4*)(hp + 12);
  }

  const char* wsrc = (const char*)(Wbf + ((size_t)k*128 + (size_t)(kb&3)*32) * 4480);

  #pragma unroll
  for (int rr = 0; rr < 3; rr++){
    int u = tid + rr*256;
    if (u < 560)
      __builtin_amdgcn_global_load_lds(
        (const __attribute__((address_space(1))) unsigned int*)(wsrc + (size_t)u*16),
        (__attribute__((address_space(3))) unsigned int*)((char*)&Wlds[0][0] + u*16),
        16, 0, 0);
  }

  f32x4 acc[2][7];
  #pragma unroll
  for (int m = 0; m < 2; m++)
    #pragma unroll
    for (int n = 0; n < 7; n++)
      acc[m][n] = (f32x4){0.f,0.f,0.f,0.f};

  __syncthreads();

  #pragma unroll
  for (int c = 0; c < 32; c++){
    int cur = c & 1;
    if (c < 31){
      const char* nsrc = wsrc + (size_t)(c+1)*8960;
      #pragma unroll
      for (int rr = 0; rr < 3; rr++){
        int u = tid + rr*256;
        if (u < 560)
          __builtin_amdgcn_global_load_lds(
            (const __attribute__((address_space(1))) unsigned int*)(nsrc + (size_t)u*16),
            (__attribute__((address_space(3))) unsigned int*)((char*)&Wlds[cur^1][0] + u*16),
            16, 0, 0);
      }
    }
    const int ci = c >> 1, cj = c & 1;
    short8 af[2];
    #pragma unroll
    for (int m = 0; m < 2; m++){
      float hv = ((const float*)&hsr[m][ci>>2])[ci&3];
      float4 t0 = tsr[m][cj][0];
      float4 t1 = tsr[m][cj][1];
      af[m][0] = (short)f2bf(hv*t0.x);
      af[m][1] = (short)f2bf(hv*t0.y);
      af[m][2] = (short)f2bf(hv*t0.z);
      af[m][3] = (short)f2bf(hv*t0.w);
      af[m][4] = (short)f2bf(hv*t1.x);
      af[m][5] = (short)f2bf(hv*t1.y);
      af[m][6] = (short)f2bf(hv*t1.z);
      af[m][7] = (short)f2bf(hv*t1.w);
    }
    #pragma unroll
    for (int n = 0; n < 7; n++){
      short8 bfr = *(const short8*)&Wlds[cur][(n*16 + row16)*40 + oct*8];
      acc[0][n] = __builtin_amdgcn_mfma_f32_16x16x32_bf16(af[0], bfr, acc[0][n], 0, 0, 0);
      acc[1][n] = __builtin_amdgcn_mfma_f32_16x16x32_bf16(af[1], bfr, acc[1][n], 0, 0, 0);
    }
    __syncthreads();
  }

  float* pk = partial + (size_t)kb*Rc*NLc;
  #pragma unroll
  for (int m = 0; m < 2; m++){
    #pragma unroll
    for (int n = 0; n < 7; n++){
      #pragma unroll
      for (int j = 0; j < 4; j++){
        int r = rbase + m*16 + oct*4 + j;
        int col = n*16 + row16;
        if (r < Rc && col < NLc)
          pk[(size_t)r*NLc + col] = acc[m][n][j];
      }
    }
  }
}

// K9: sum partials + bias
__global__ __launch_bounds__(256) void k_reduce(const float* __restrict__ partial,
                                                const float* __restrict__ bilb,
                                                float* __restrict__ out){
  int idx = blockIdx.x*256 + threadIdx.x;
  if (idx >= Rc*NLc) return;
  int n = idx % NLc;
  float s = bilb[n];
  #pragma unroll
  for (int ks = 0; ks < KSPL; ks++) s += partial[(size_t)ks*Rc*NLc + idx];
  out[idx] = s;
}

extern "C" void kernel_launch(void* const* d_in, const int* in_sizes, int n_in,
                              void* d_out, int out_size, void* d_ws, size_t ws_size,
                              hipStream_t stream){
  const float* seq   = (const float*)d_in[0];
  const float* att   = (const float*)d_in[1];
  const float* W_q   = (const float*)d_in[2];
  const float* W_k   = (const float*)d_in[3];
  const float* headW = (const float*)d_in[4];
  const float* headb = (const float*)d_in[5];
  const float* tailW = (const float*)d_in[6];
  const float* tailb = (const float*)d_in[7];
  const float* bilW  = (const float*)d_in[8];
  const float* bilb  = (const float*)d_in[9];
  const int*   mpos  = (const int*)d_in[10];
  const int*   hts   = (const int*)d_in[11];
  float* out = (float*)d_out;

  float* ws = (float*)d_ws;
  float* ent_att = ws;                                      // 1,179,648 f
  float* q_c     = ws + 1179648;                            // 1,695,744 f
  float* kment   = q_c + 1695744;                           //   294,912 f
  float* ment    = kment + 294912;                          //   294,912 f
  unsigned short* seqt    = (unsigned short*)(ment + 294912);   // 3,145,728 u16
  unsigned short* htbf    = seqt + 3145728;                     // 2,260,992
  unsigned short* rs_bf   = htbf + 2260992;                     // 1,695,744
  unsigned short* ment_bf = rs_bf + 1695744;                    //   294,912
  unsigned short* h_bf    = ment_bf + 294912;                   // 1,695,744
  unsigned short* t_bf    = h_bf + 1695744;                     // 1,695,744
  unsigned short* Wq_t    = t_bf + 1695744;                     //   589,824
  unsigned short* Wk_t    = Wq_t + 589824;                      //   589,824
  unsigned short* headW_t = Wk_t + 589824;                      // 1,179,648
  unsigned short* tailW_t = headW_t + 1179648;                  // 1,179,648
  float* hsb = (float*)(tailW_t + 1179648);                 // = ws + 10,629,120
  float* tsb = hsb + 1695744;
  unsigned short* Wbf = (unsigned short*)(tsb + 1695744);   // 6,881,280 u16
  float* partial = ws;   // bilinear partials (10,280,448 f) overlap dead region (10,629,120 f)

  k_wconv  <<<1536, 256, 0, stream>>>(bilW, Wbf);
  k_tcvt   <<<dim3(16,12,4), 256, 0, stream>>>(seq, seqt, Lc, Dc,
                                               (size_t)Lc*Dc, (size_t)Dc*Lc);
  k_tcvt   <<<dim3(12,12,1), 256, 0, stream>>>(W_q, Wq_t, Dc, Dc, 0, 0);
  k_tcvt   <<<dim3(12,12,1), 256, 0, stream>>>(W_k, Wk_t, Dc, Dc, 0, 0);
  k_tcvt   <<<dim3(24,12,1), 256, 0, stream>>>(headW, headW_t, 2*Dc, Dc, 0, 0);
  k_tcvt   <<<dim3(24,12,1), 256, 0, stream>>>(tailW, tailW_t, 2*Dc, Dc, 0, 0);
  k_ent_att<<<Bc*Ec*Hc, 256, 0, stream>>>(att, mpos, ent_att);
  k_ht_att <<<Rc, 256, 0, stream>>>(ent_att, hts, htbf);
  k_rs_mfma<<<dim3(5,12,4), 256, 0, stream>>>(htbf, seqt, rs_bf);
  k_gather <<<(Bc*Ec*Mc*Dc)/256, 256, 0, stream>>>(seq, mpos, ment, ment_bf);
  k_gemm   <<<dim3(3,12), 256, 0, stream>>>(ment_bf, nullptr, 0, Wk_t, nullptr, kment, Bc*Ec*Mc, 0);
  k_gemm   <<<dim3(18,12), 256, 0, stream>>>(rs_bf, nullptr, 0, Wq_t, nullptr, q_c, Rc, 0);
  k_pool   <<<Rc, 256, 0, stream>>>(kment, ment, q_c, hts, h_bf, t_bf);
  k_gemm   <<<dim3(18,12), 256, 0, stream>>>(h_bf, rs_bf, Dc, headW_t, headb, hsb, Rc, 1);
  k_gemm   <<<dim3(18,12), 256, 0, stream>>>(t_bf, rs_bf, Dc, tailW_t, tailb, tsb, Rc, 1);
  k_bilinear_mfma<<<18*KSPL, 256, 0, stream>>>(hsb, tsb, Wbf, partial);
  k_reduce <<<(Rc*NLc+255)/256, 256, 0, stream>>>(partial, bilb, out);
}

// Round 4
// 262.950 us; speedup vs baseline: 5.1818x; 1.2408x over previous
//
#include <hip/hip_runtime.h>
#include <hip/hip_bf16.h>
#include <math.h>

#define Bc 4
#define Lc 1024
#define Dc 768
#define Hc 12
#define Ec 24
#define Mc 4
#define Pc 552
#define EMBc 768
#define NLc 97
#define Rc (Bc*Pc)      // 2208
#define KSPL 24         // bilinear: 12 k-blocks x 2 splits of i; kb%8 == blockIdx%8 (XCD-local W)

typedef __attribute__((ext_vector_type(4))) float f32x4;
typedef __attribute__((ext_vector_type(8))) short short8;

static __device__ __forceinline__ unsigned short f2bf(float x){
  unsigned int u = __float_as_uint(x);
  unsigned int r = u + 0x7fffu + ((u >> 16) & 1u);   // RNE
  return (unsigned short)(r >> 16);
}
static __device__ __forceinline__ unsigned short f2bf_hw(float x){
  __hip_bfloat16 h = __float2bfloat16(x);            // hw RNE cvt
  return __builtin_bit_cast(unsigned short, h);
}

// ---------------- K0: fused weight prep ----------------
// bx<1536: bilinear W chunk -> bf16 [n=112][kk=40]; then 5 transpose+cvt jobs
__global__ __launch_bounds__(256) void k_prep(const float* __restrict__ bilW, unsigned short* __restrict__ Wbf,
                                              const float* __restrict__ seq, unsigned short* __restrict__ seqt,
                                              const float* __restrict__ W_q, unsigned short* __restrict__ Wq_t,
                                              const float* __restrict__ W_k, unsigned short* __restrict__ Wk_t,
                                              const float* __restrict__ headW, unsigned short* __restrict__ headW_t,
                                              const float* __restrict__ tailW, unsigned short* __restrict__ tailW_t){
  int bx = blockIdx.x;
  if (bx < 1536){
    const float* Ws = bilW + (size_t)bx*32*NLc;
    unsigned short* o = Wbf + (size_t)bx*4480;
    for (int idx = threadIdx.x; idx < 112*32; idx += 256){
      int n = idx % 112, kk = idx / 112;
      float v = (n < NLc) ? Ws[(size_t)kk*NLc + n] : 0.f;
      o[n*40 + kk] = f2bf(v);
    }
    return;
  }
  bx -= 1536;
  const float* src; unsigned short* dst; int rows, cols, r0, c0;
  if (bx < 768){           // seq [1024x768] x4 -> seqt [768x1024]
    int z = bx / 192, rem = bx % 192;
    src = seq + (size_t)z*Lc*Dc; dst = seqt + (size_t)z*Dc*Lc;
    rows = Lc; cols = Dc; r0 = (rem % 16)*64; c0 = (rem / 16)*64;
  } else if (bx < 768+144){
    int rem = bx - 768;
    src = W_q; dst = Wq_t; rows = Dc; cols = Dc; r0 = (rem % 12)*64; c0 = (rem / 12)*64;
  } else if (bx < 768+288){
    int rem = bx - (768+144);
    src = W_k; dst = Wk_t; rows = Dc; cols = Dc; r0 = (rem % 12)*64; c0 = (rem / 12)*64;
  } else if (bx < 768+288+288){
    int rem = bx - (768+288);
    src = headW; dst = headW_t; rows = 2*Dc; cols = Dc; r0 = (rem % 24)*64; c0 = (rem / 24)*64;
  } else {
    int rem = bx - (768+288+288);
    src = tailW; dst = tailW_t; rows = 2*Dc; cols = Dc; r0 = (rem % 24)*64; c0 = (rem / 24)*64;
  }
  __shared__ float t[64][65];
  #pragma unroll
  for (int q = 0; q < 16; q++){
    int idx = q*256 + threadIdx.x;
    int rr = idx >> 6, cc = idx & 63;
    t[rr][cc] = src[(size_t)(r0+rr)*cols + c0+cc];
  }
  __syncthreads();
  #pragma unroll
  for (int q = 0; q < 16; q++){
    int idx = q*256 + threadIdx.x;
    int cc = idx >> 6, rr = idx & 63;
    dst[(size_t)(c0+cc)*rows + r0+rr] = f2bf(t[rr][cc]);
  }
}

// ---------------- K1: ent_att + mention gather (fused) ----------------
__global__ __launch_bounds__(256) void k_ent_att(const float* __restrict__ att,
                                                 const int* __restrict__ mpos,
                                                 const float* __restrict__ seq,
                                                 float* __restrict__ ent_att,
                                                 float* __restrict__ ment,
                                                 unsigned short* __restrict__ ment_bf){
  int blk = blockIdx.x;             // (b*E+e)*H + h, 1152 blocks
  int h  = blk % Hc;
  int be = blk / Hc;
  int b  = be / Ec;
  int p0 = mpos[be*Mc+0]+1, p1 = mpos[be*Mc+1]+1;
  int p2 = mpos[be*Mc+2]+1, p3 = mpos[be*Mc+3]+1;
  const float* ab = att + ((size_t)b*Hc + h)*Lc*Lc;
  const float* a0 = ab + (size_t)p0*Lc;
  const float* a1 = ab + (size_t)p1*Lc;
  const float* a2 = ab + (size_t)p2*Lc;
  const float* a3 = ab + (size_t)p3*Lc;
  float* o = ent_att + (size_t)blk*Lc;
  for (int l = threadIdx.x; l < Lc; l += 256)
    o[l] = 0.25f*(a0[l]+a1[l]+a2[l]+a3[l]);
  // gather: 1152*256 == B*E*M*D
  int gidx = blk*256 + threadIdx.x;
  int d = gidx % Dc;
  int bem = gidx / Dc;
  int bb = bem / (Ec*Mc);
  int pos = mpos[bem] + 1;
  float v = seq[((size_t)bb*Lc + pos)*Dc + d];
  ment[gidx] = v;
  ment_bf[gidx] = f2bf(v);
}

// ---------------- K2: ht_att -> bf16, XCD-aligned batches ----------------
__global__ __launch_bounds__(256) void k_ht_att(const float* __restrict__ ent_att,
                                                const int* __restrict__ hts,
                                                unsigned short* __restrict__ htbf){
  int b = blockIdx.x & 3;           // XCD = bid%8 -> batch = XCD&3 (ent_att L2-local)
  int p = blockIdx.x >> 2;
  int r = b*Pc + p;
  int hi = hts[r*2+0], ti = hts[r*2+1];
  const float* eh = ent_att + (size_t)(b*Ec+hi)*Hc*Lc;
  const float* et = ent_att + (size_t)(b*Ec+ti)*Hc*Lc;
  __shared__ float raw[Lc];
  __shared__ float wsum[4];
  int l4 = threadIdx.x*4;
  float4 s4 = {0.f,0.f,0.f,0.f};
  #pragma unroll
  for (int h = 0; h < Hc; h++){
    float4 e1 = *(const float4*)&eh[h*Lc + l4];
    float4 e2 = *(const float4*)&et[h*Lc + l4];
    s4.x = fmaf(e1.x,e2.x,s4.x); s4.y = fmaf(e1.y,e2.y,s4.y);
    s4.z = fmaf(e1.z,e2.z,s4.z); s4.w = fmaf(e1.w,e2.w,s4.w);
  }
  s4.x *= (1.0f/Hc); s4.y *= (1.0f/Hc); s4.z *= (1.0f/Hc); s4.w *= (1.0f/Hc);
  *(float4*)&raw[l4] = s4;
  float lsum = s4.x+s4.y+s4.z+s4.w;
  for (int off = 32; off; off >>= 1) lsum += __shfl_down(lsum, off);
  if ((threadIdx.x & 63) == 0) wsum[threadIdx.x>>6] = lsum;
  __syncthreads();
  float inv = 1.0f/(wsum[0]+wsum[1]+wsum[2]+wsum[3] + 1e-5f);
  unsigned short* o = htbf + (size_t)r*Lc;
  float4 rv = *(const float4*)&raw[l4];
  unsigned short ov[4] = { f2bf(rv.x*inv), f2bf(rv.y*inv), f2bf(rv.z*inv), f2bf(rv.w*inv) };
  *(ushort2*)&o[l4]   = *(ushort2*)&ov[0];
  *(ushort2*)&o[l4+2] = *(ushort2*)&ov[2];
}

// ---------------- K3 (MFMA): rs_bf[b][p][d] = sum_l htbf*seqt ----------------
__global__ __launch_bounds__(256) void k_rs_mfma(const unsigned short* __restrict__ htbf,
                                                 const unsigned short* __restrict__ seqt,
                                                 unsigned short* __restrict__ rs_bf){
  int b = blockIdx.z;
  const unsigned short* A = htbf + (size_t)b*Pc*Lc;
  const unsigned short* Wt = seqt + (size_t)b*Dc*Lc;
  unsigned short* C = rs_bf + (size_t)b*Pc*Dc;
  int lane = threadIdx.x & 63, wid = threadIdx.x >> 6;
  int row16 = lane & 15, oct = lane >> 4;
  int rbase = blockIdx.x*128 + wid*32;
  int r0 = rbase + row16;      if (r0 > Pc-1) r0 = Pc-1;
  int r1 = rbase + 16 + row16; if (r1 > Pc-1) r1 = Pc-1;
  const unsigned short* a0p = A + (size_t)r0*Lc + oct*8;
  const unsigned short* a1p = A + (size_t)r1*Lc + oct*8;
  const unsigned short* wp  = Wt + (size_t)(blockIdx.y*64 + row16)*Lc + oct*8;
  f32x4 acc[2][4];
  #pragma unroll
  for (int m = 0; m < 2; m++)
    #pragma unroll
    for (int n = 0; n < 4; n++) acc[m][n] = (f32x4){0.f,0.f,0.f,0.f};
  #pragma unroll 4
  for (int kc = 0; kc < Lc; kc += 32){
    short8 a0 = *(const short8*)(a0p + kc);
    short8 a1 = *(const short8*)(a1p + kc);
    #pragma unroll
    for (int n = 0; n < 4; n++){
      short8 bv = *(const short8*)(wp + (size_t)n*16*Lc + kc);
      acc[0][n] = __builtin_amdgcn_mfma_f32_16x16x32_bf16(a0, bv, acc[0][n], 0, 0, 0);
      acc[1][n] = __builtin_amdgcn_mfma_f32_16x16x32_bf16(a1, bv, acc[1][n], 0, 0, 0);
    }
  }
  #pragma unroll
  for (int m = 0; m < 2; m++)
    #pragma unroll
    for (int n = 0; n < 4; n++)
      #pragma unroll
      for (int j = 0; j < 4; j++){
        int r = rbase + m*16 + oct*4 + j;
        if (r < Pc){
          int col = blockIdx.y*64 + n*16 + row16;
          C[(size_t)r*Dc + col] = f2bf(acc[m][n][j]);
        }
      }
}

// ---------------- K4: generic MFMA GEMM, 2 jobs per launch ----------------
struct GemmJob {
  const unsigned short* A1; const unsigned short* A2; int K2;
  const unsigned short* Wt; const float* bias; float* C; int M; int do_tanh;
};

__global__ __launch_bounds__(256) void k_gemm(GemmJob j0, GemmJob j1, int nx0){
  GemmJob j = (blockIdx.x < nx0) ? j0 : j1;
  int mbx = (blockIdx.x < nx0) ? blockIdx.x : blockIdx.x - nx0;
  const int Ktot = Dc + j.K2;
  int lane = threadIdx.x & 63, wid = threadIdx.x >> 6;
  int row16 = lane & 15, oct = lane >> 4;
  int rbase = mbx*128 + wid*32;
  int r0 = rbase + row16;      if (r0 > j.M-1) r0 = j.M-1;
  int r1 = rbase + 16 + row16; if (r1 > j.M-1) r1 = j.M-1;
  const unsigned short* a0p = j.A1 + (size_t)r0*Dc + oct*8;
  const unsigned short* a1p = j.A1 + (size_t)r1*Dc + oct*8;
  const unsigned short* wp  = j.Wt + (size_t)(blockIdx.y*64 + row16)*Ktot + oct*8;
  f32x4 acc[2][4];
  #pragma unroll
  for (int m = 0; m < 2; m++)
    #pragma unroll
    for (int n = 0; n < 4; n++) acc[m][n] = (f32x4){0.f,0.f,0.f,0.f};
  #pragma unroll 4
  for (int kc = 0; kc < Dc; kc += 32){
    short8 a0 = *(const short8*)(a0p + kc);
    short8 a1 = *(const short8*)(a1p + kc);
    #pragma unroll
    for (int n = 0; n < 4; n++){
      short8 bv = *(const short8*)(wp + (size_t)n*16*Ktot + kc);
      acc[0][n] = __builtin_amdgcn_mfma_f32_16x16x32_bf16(a0, bv, acc[0][n], 0, 0, 0);
      acc[1][n] = __builtin_amdgcn_mfma_f32_16x16x32_bf16(a1, bv, acc[1][n], 0, 0, 0);
    }
  }
  if (j.K2 > 0){
    const unsigned short* b0p = j.A2 + (size_t)r0*Dc + oct*8;
    const unsigned short* b1p = j.A2 + (size_t)r1*Dc + oct*8;
    const unsigned short* wp2 = wp + Dc;
    #pragma unroll 4
    for (int kc = 0; kc < Dc; kc += 32){
      short8 a0 = *(const short8*)(b0p + kc);
      short8 a1 = *(const short8*)(b1p + kc);
      #pragma unroll
      for (int n = 0; n < 4; n++){
        short8 bv = *(const short8*)(wp2 + (size_t)n*16*Ktot + kc);
        acc[0][n] = __builtin_amdgcn_mfma_f32_16x16x32_bf16(a0, bv, acc[0][n], 0, 0, 0);
        acc[1][n] = __builtin_amdgcn_mfma_f32_16x16x32_bf16(a1, bv, acc[1][n], 0, 0, 0);
      }
    }
  }
  #pragma unroll
  for (int m = 0; m < 2; m++)
    #pragma unroll
    for (int n = 0; n < 4; n++)
      #pragma unroll
      for (int j4 = 0; j4 < 4; j4++){
        int r = rbase + m*16 + oct*4 + j4;
        if (r < j.M){
          int col = blockIdx.y*64 + n*16 + row16;
          float v = acc[m][n][j4];
          if (j.bias) v += j.bias[col];
          if (j.do_tanh) v = tanhf(v);
          j.C[(size_t)r*Dc + col] = v;
        }
      }
}

// ---------------- K6: pool (softmax over M=4, both sides) ----------------
__global__ __launch_bounds__(256) void k_pool(const float* __restrict__ kment,
                                              const float* __restrict__ ment,
                                              const float* __restrict__ q_c,
                                              const int* __restrict__ hts,
                                              unsigned short* __restrict__ h_bf,
                                              unsigned short* __restrict__ t_bf){
  int r = blockIdx.x;
  int b = r / Pc;
  __shared__ float q[Dc];
  __shared__ float sred[16];
  __shared__ float sw[Mc];
  for (int d = threadIdx.x; d < Dc; d += 256) q[d] = q_c[(size_t)r*Dc + d];
  __syncthreads();
  const float invs = 0.03608439182435161f;  // 1/sqrt(768)
  for (int side = 0; side < 2; side++){
    int e = hts[r*2+side];
    const float* kb = kment + (size_t)(b*Ec+e)*Mc*Dc;
    const float* mb = ment  + (size_t)(b*Ec+e)*Mc*Dc;
    float part[Mc] = {0.f,0.f,0.f,0.f};
    for (int d = threadIdx.x; d < Dc; d += 256){
      float qv = q[d];
      #pragma unroll
      for (int m = 0; m < Mc; m++) part[m] = fmaf(kb[m*Dc+d], qv, part[m]);
    }
    #pragma unroll
    for (int m = 0; m < Mc; m++)
      for (int off = 32; off; off >>= 1) part[m] += __shfl_down(part[m], off);
    if ((threadIdx.x & 63) == 0){
      int w = threadIdx.x >> 6;
      #pragma unroll
      for (int m = 0; m < Mc; m++) sred[w*4+m] = part[m];
    }
    __syncthreads();
    if (threadIdx.x == 0){
      float sc[Mc]; float mx = -1e30f;
      for (int m = 0; m < Mc; m++){
        sc[m] = (sred[m]+sred[4+m]+sred[8+m]+sred[12+m])*invs;
        mx = fmaxf(mx, sc[m]);
      }
      float ssum = 0.f;
      for (int m = 0; m < Mc; m++){ sc[m] = expf(sc[m]-mx); ssum += sc[m]; }
      float isum = 1.0f/ssum;
      for (int m = 0; m < Mc; m++) sw[m] = sc[m]*isum;
    }
    __syncthreads();
    float w0 = sw[0], w1 = sw[1], w2 = sw[2], w3 = sw[3];
    unsigned short* o = (side ? t_bf : h_bf) + (size_t)r*Dc;
    for (int d = threadIdx.x; d < Dc; d += 256)
      o[d] = f2bf(w0*mb[d] + w1*mb[Dc+d] + w2*mb[2*Dc+d] + w3*mb[3*Dc+d]);
    __syncthreads();
  }
}

// ---------------- K8: MFMA bilinear, KSPL=24, XCD-local W ----------------
// grid = mb(18) x kb(24), blockIdx = mb*24+kb -> XCD = kb%8 (same-kb blocks share L2)
__global__ __launch_bounds__(256) void k_bilinear_mfma(
    const float* __restrict__ hs, const float* __restrict__ ts,
    const unsigned short* __restrict__ Wbf,
    float* __restrict__ partial)
{
  int mb = blockIdx.x / KSPL;
  int kb = blockIdx.x % KSPL;
  int k  = kb >> 1;             // EMB block 0..11
  int i0 = (kb & 1) * 32;       // i sub-range (32 wide)

  int tid  = threadIdx.x;
  int lane = tid & 63;
  int wid  = tid >> 6;
  int row16 = lane & 15;
  int oct   = lane >> 4;

  int rbase = mb*128 + wid*32;

  __shared__ __align__(16) unsigned short Wlds[2][4480];

  float4 tsr[2][2][2];   // [m][jhalf][q]
  float4 hsr[2][8];      // [m][q]: hs[r][k*64+i0 .. +31]
  #pragma unroll
  for (int m = 0; m < 2; m++){
    int r = rbase + m*16 + row16; if (r > Rc-1) r = Rc-1;
    const float* tp = ts + (size_t)r*EMBc + k*64;
    tsr[m][0][0] = *(const float4*)(tp + oct*8);
    tsr[m][0][1] = *(const float4*)(tp + oct*8 + 4);
    tsr[m][1][0] = *(const float4*)(tp + 32 + oct*8);
    tsr[m][1][1] = *(const float4*)(tp + 32 + oct*8 + 4);
    const float* hp = hs + (size_t)r*EMBc + k*64 + i0;
    #pragma unroll
    for (int q = 0; q < 8; q++) hsr[m][q] = *(const float4*)(hp + q*4);
  }

  const char* wsrc = (const char*)(Wbf + ((size_t)(k*128 + i0*2))*4480);

  #pragma unroll
  for (int rr = 0; rr < 3; rr++){
    int u = tid + rr*256;
    if (u < 560)
      __builtin_amdgcn_global_load_lds(
        (const __attribute__((address_space(1))) unsigned int*)(wsrc + (size_t)u*16),
        (__attribute__((address_space(3))) unsigned int*)((char*)&Wlds[0][0] + u*16),
        16, 0, 0);
  }

  f32x4 acc[2][7];
  #pragma unroll
  for (int m = 0; m < 2; m++)
    #pragma unroll
    for (int n = 0; n < 7; n++)
      acc[m][n] = (f32x4){0.f,0.f,0.f,0.f};

  __syncthreads();   // chunk 0 staged

  #pragma unroll 2
  for (int c = 0; c < 64; c++){
    int cur = c & 1;
    if (c < 63){
      const char* nsrc = wsrc + (size_t)(c+1)*8960;
      #pragma unroll
      for (int rr = 0; rr < 3; rr++){
        int u = tid + rr*256;
        if (u < 560)
          __builtin_amdgcn_global_load_lds(
            (const __attribute__((address_space(1))) unsigned int*)(nsrc + (size_t)u*16),
            (__attribute__((address_space(3))) unsigned int*)((char*)&Wlds[cur^1][0] + u*16),
            16, 0, 0);
      }
    }
    const int ci = c >> 1, cj = c & 1;
    short8 af[2];
    #pragma unroll
    for (int m = 0; m < 2; m++){
      float hv = ((const float*)&hsr[m][ci>>2])[ci&3];
      float4 t0 = tsr[m][cj][0];
      float4 t1 = tsr[m][cj][1];
      af[m][0] = (short)f2bf_hw(hv*t0.x);
      af[m][1] = (short)f2bf_hw(hv*t0.y);
      af[m][2] = (short)f2bf_hw(hv*t0.z);
      af[m][3] = (short)f2bf_hw(hv*t0.w);
      af[m][4] = (short)f2bf_hw(hv*t1.x);
      af[m][5] = (short)f2bf_hw(hv*t1.y);
      af[m][6] = (short)f2bf_hw(hv*t1.z);
      af[m][7] = (short)f2bf_hw(hv*t1.w);
    }
    #pragma unroll
    for (int n = 0; n < 7; n++){
      short8 bfr = *(const short8*)&Wlds[cur][(n*16 + row16)*40 + oct*8];
      acc[0][n] = __builtin_amdgcn_mfma_f32_16x16x32_bf16(af[0], bfr, acc[0][n], 0, 0, 0);
      acc[1][n] = __builtin_amdgcn_mfma_f32_16x16x32_bf16(af[1], bfr, acc[1][n], 0, 0, 0);
    }
    __syncthreads();
  }

  float* pk = partial + (size_t)kb*Rc*NLc;
  #pragma unroll
  for (int m = 0; m < 2; m++){
    #pragma unroll
    for (int n = 0; n < 7; n++){
      #pragma unroll
      for (int j = 0; j < 4; j++){
        int r = rbase + m*16 + oct*4 + j;
        int col = n*16 + row16;
        if (r < Rc && col < NLc)
          pk[(size_t)r*NLc + col] = acc[m][n][j];
      }
    }
  }
}

// ---------------- K9: sum partials + bias ----------------
__global__ __launch_bounds__(256) void k_reduce(const float* __restrict__ partial,
                                                const float* __restrict__ bilb,
                                                float* __restrict__ out){
  int idx = blockIdx.x*256 + threadIdx.x;
  if (idx >= Rc*NLc) return;
  int n = idx % NLc;
  float s = bilb[n];
  #pragma unroll
  for (int ks = 0; ks < KSPL; ks++) s += partial[(size_t)ks*Rc*NLc + idx];
  out[idx] = s;
}

extern "C" void kernel_launch(void* const* d_in, const int* in_sizes, int n_in,
                              void* d_out, int out_size, void* d_ws, size_t ws_size,
                              hipStream_t stream){
  const float* seq   = (const float*)d_in[0];
  const float* att   = (const float*)d_in[1];
  const float* W_q   = (const float*)d_in[2];
  const float* W_k   = (const float*)d_in[3];
  const float* headW = (const float*)d_in[4];
  const float* headb = (const float*)d_in[5];
  const float* tailW = (const float*)d_in[6];
  const float* tailb = (const float*)d_in[7];
  const float* bilW  = (const float*)d_in[8];
  const float* bilb  = (const float*)d_in[9];
  const int*   mpos  = (const int*)d_in[10];
  const int*   hts   = (const int*)d_in[11];
  float* out = (float*)d_out;

  float* ws = (float*)d_ws;
  float* ent_att = ws;                                      // 1,179,648 f
  float* q_c     = ws + 1179648;                            // 1,695,744 f
  float* kment   = q_c + 1695744;                           //   294,912 f
  float* ment    = kment + 294912;                          //   294,912 f
  unsigned short* seqt    = (unsigned short*)(ment + 294912);   // 3,145,728 u16
  unsigned short* htbf    = seqt + 3145728;                     // 2,260,992
  unsigned short* rs_bf   = htbf + 2260992;                     // 1,695,744
  unsigned short* ment_bf = rs_bf + 1695744;                    //   294,912
  unsigned short* h_bf    = ment_bf + 294912;                   // 1,695,744
  unsigned short* t_bf    = h_bf + 1695744;                     // 1,695,744
  unsigned short* Wq_t    = t_bf + 1695744;                     //   589,824
  unsigned short* Wk_t    = Wq_t + 589824;                      //   589,824
  unsigned short* headW_t = Wk_t + 589824;                      // 1,179,648
  unsigned short* tailW_t = headW_t + 1179648;                  // 1,179,648
  float* hsb = (float*)(tailW_t + 1179648);                 // = ws + 10,629,120
  float* tsb = hsb + 1695744;
  unsigned short* Wbf = (unsigned short*)(tsb + 1695744);   // 6,881,280 u16
  float* partial = ws;   // 24*2208*97 = 5,140,224 f, overlaps dead prefix region

  k_prep   <<<3168, 256, 0, stream>>>(bilW, Wbf, seq, seqt, W_q, Wq_t, W_k, Wk_t,
                                      headW, headW_t, tailW, tailW_t);
  k_ent_att<<<Bc*Ec*Hc, 256, 0, stream>>>(att, mpos, seq, ent_att, ment, ment_bf);
  k_ht_att <<<Rc, 256, 0, stream>>>(ent_att, hts, htbf);
  k_rs_mfma<<<dim3(5,12,4), 256, 0, stream>>>(htbf, seqt, rs_bf);
  {
    GemmJob jq  = { rs_bf,   nullptr, 0, Wq_t, nullptr, q_c,   Rc,        0 };
    GemmJob jk  = { ment_bf, nullptr, 0, Wk_t, nullptr, kment, Bc*Ec*Mc,  0 };
    k_gemm <<<dim3(21,12), 256, 0, stream>>>(jq, jk, 18);
  }
  k_pool   <<<Rc, 256, 0, stream>>>(kment, ment, q_c, hts, h_bf, t_bf);
  {
    GemmJob jh = { h_bf, rs_bf, Dc, headW_t, headb, hsb, Rc, 1 };
    GemmJob jt = { t_bf, rs_bf, Dc, tailW_t, tailb, tsb, Rc, 1 };
    k_gemm <<<dim3(36,12), 256, 0, stream>>>(jh, jt, 18);
  }
  k_bilinear_mfma<<<18*KSPL, 256, 0, stream>>>(hsb, tsb, Wbf, partial);
  k_reduce <<<(Rc*NLc+255)/256, 256, 0, stream>>>(partial, bilb, out);
}